// Round 1
// baseline (2256.369 us; speedup 1.0000x reference)
//
#include <hip/hip_runtime.h>
#include <hip/hip_bf16.h>
#include <cstddef>

// Problem constants: B=8, L=512, H=768, DIN=1536, N=64, R=48, Kc=4. M = B*L = 4096.

#define BM 64
#define BN 64
#define BK 16

// Generic tiled fp32 GEMM.
// AMODE 0: A[row*lda + k]
// AMODE 1: A = concat(text,audio,video) along k (each segment width 768, tiles never straddle)
// AMODE 2: A[row][k] = A0[((row>>9)*1536 + k)*512 + (row&511)]   (scan output layout [B][DIN][L])
// EPI 0: C = acc
// EPI 1: C = acc + bias[col]
// EPI 2: C = softplus(acc + bias[col])
// EPI 3: C = acc + resid[row*ldc + col]
template<int AMODE, int EPI>
__global__ __launch_bounds__(256) void gemm_k(
    const float* __restrict__ A0, const float* __restrict__ A1, const float* __restrict__ A2,
    const float* __restrict__ Bmat, const float* __restrict__ bias,
    const float* __restrict__ resid, float* __restrict__ C,
    int M, int N, int K, int lda, int ldc)
{
  __shared__ float As[BK][BM + 4];
  __shared__ float Bs[BK][BN + 4];
  const int tid = threadIdx.x;
  const int bm = blockIdx.x * BM;
  const int bn = blockIdx.y * BN;
  const int tx = tid & 15, ty = tid >> 4;
  float acc[4][4] = {};

  for (int k0 = 0; k0 < K; k0 += BK) {
    // ---- A tile -> As[k][m] ----
    if (AMODE == 0) {
      #pragma unroll
      for (int e = tid; e < BM * BK; e += 256) {
        int m = e >> 4, kk = e & 15;
        As[kk][m] = A0[(size_t)(bm + m) * lda + (k0 + kk)];
      }
    } else if (AMODE == 1) {
      int seg = k0 / 768;
      const float* Aseg = (seg == 0) ? A0 : (seg == 1) ? A1 : A2;
      int kbase = k0 - seg * 768;
      #pragma unroll
      for (int e = tid; e < BM * BK; e += 256) {
        int m = e >> 4, kk = e & 15;
        As[kk][m] = Aseg[(size_t)(bm + m) * 768 + (kbase + kk)];
      }
    } else {
      #pragma unroll
      for (int e = tid; e < BM * BK; e += 256) {
        int kk = e >> 6, m = e & 63;
        int row = bm + m;
        As[kk][m] = A0[((size_t)(row >> 9) * 1536 + (k0 + kk)) * 512 + (row & 511)];
      }
    }
    // ---- B tile -> Bs[k][n] ----
    #pragma unroll
    for (int e = tid; e < BK * BN; e += 256) {
      int kk = e >> 6, n = e & 63;
      int col = bn + n;
      Bs[kk][n] = (col < N) ? Bmat[(size_t)(k0 + kk) * N + col] : 0.f;
    }
    __syncthreads();
    #pragma unroll
    for (int kk = 0; kk < BK; ++kk) {
      const float4 a4 = *reinterpret_cast<const float4*>(&As[kk][ty * 4]);
      const float4 b4 = *reinterpret_cast<const float4*>(&Bs[kk][tx * 4]);
      float a[4] = {a4.x, a4.y, a4.z, a4.w};
      float b[4] = {b4.x, b4.y, b4.z, b4.w};
      #pragma unroll
      for (int i = 0; i < 4; ++i)
        #pragma unroll
        for (int j = 0; j < 4; ++j)
          acc[i][j] = fmaf(a[i], b[j], acc[i][j]);
    }
    __syncthreads();
  }

  #pragma unroll
  for (int i = 0; i < 4; ++i) {
    int row = bm + ty * 4 + i;
    #pragma unroll
    for (int j = 0; j < 4; ++j) {
      int col = bn + tx * 4 + j;
      if (col < N) {
        float v = acc[i][j];
        if (EPI == 1) v += bias[col];
        if (EPI == 2) {
          v += bias[col];
          v = fmaxf(v, 0.f) + log1pf(expf(-fabsf(v)));  // stable softplus
        }
        if (EPI == 3) v += resid[(size_t)row * ldc + col];
        C[(size_t)row * ldc + col] = v;
      }
    }
  }
}

__device__ inline float block_sum256(float s, float* red) {
  #pragma unroll
  for (int o = 32; o > 0; o >>= 1) s += __shfl_xor(s, o, 64);
  int tid = threadIdx.x;
  __syncthreads();  // protect red across repeated calls
  if ((tid & 63) == 0) red[tid >> 6] = s;
  __syncthreads();
  return red[0] + red[1] + red[2] + red[3];
}

// Two chained LayerNorms over rows of 768: fused = LN1(pre), h = LN2(fused)
__global__ __launch_bounds__(256) void ln2_k(
    const float* __restrict__ pre,
    const float* __restrict__ g1, const float* __restrict__ b1,
    const float* __restrict__ g2, const float* __restrict__ b2,
    float* __restrict__ fused, float* __restrict__ hout)
{
  __shared__ float red[4];
  const int row = blockIdx.x;
  const int tid = threadIdx.x;
  const float* x = pre + (size_t)row * 768;
  float v0 = x[tid], v1 = x[tid + 256], v2 = x[tid + 512];

  float mu = block_sum256(v0 + v1 + v2, red) * (1.f / 768.f);
  float c0 = v0 - mu, c1 = v1 - mu, c2 = v2 - mu;
  float var = block_sum256(c0 * c0 + c1 * c1 + c2 * c2, red) * (1.f / 768.f);
  float r = rsqrtf(var + 1e-5f);
  float f0 = c0 * r * g1[tid] + b1[tid];
  float f1 = c1 * r * g1[tid + 256] + b1[tid + 256];
  float f2 = c2 * r * g1[tid + 512] + b1[tid + 512];
  float* fo = fused + (size_t)row * 768;
  fo[tid] = f0; fo[tid + 256] = f1; fo[tid + 512] = f2;

  float mu2 = block_sum256(f0 + f1 + f2, red) * (1.f / 768.f);
  float d0 = f0 - mu2, d1 = f1 - mu2, d2 = f2 - mu2;
  float var2 = block_sum256(d0 * d0 + d1 * d1 + d2 * d2, red) * (1.f / 768.f);
  float r2 = rsqrtf(var2 + 1e-5f);
  float* ho = hout + (size_t)row * 768;
  ho[tid]       = d0 * r2 * g2[tid] + b2[tid];
  ho[tid + 256] = d1 * r2 * g2[tid + 256] + b2[tid + 256];
  ho[tid + 512] = d2 * r2 * g2[tid + 512] + b2[tid + 512];
}

// Causal depthwise conv1d (K=4) + bias + silu. x = xz[:, :1536].
__global__ __launch_bounds__(256) void conv_k(
    const float* __restrict__ xz, const float* __restrict__ w,
    const float* __restrict__ cb, float* __restrict__ xc)
{
  int idx = blockIdx.x * 256 + threadIdx.x;  // over 4096*1536
  int row = idx / 1536;
  int d = idx - row * 1536;
  int l = row & 511, b = row >> 9;
  float acc = cb[d];
  #pragma unroll
  for (int k = 0; k < 4; ++k) {
    int lk = l - 3 + k;
    if (lk >= 0)
      acc = fmaf(xz[((size_t)(b * 512 + lk)) * 3072 + d], w[d * 4 + k], acc);
  }
  xc[idx] = acc / (1.f + __expf(-acc));  // silu
}

// Selective scan: one wave per (b,d); lane = state index n (N=64 == wave size).
// Writes y in transposed [B][DIN][L] layout (coalesced 64-step chunks).
__global__ __launch_bounds__(256) void scan_k(
    const float* __restrict__ delta, const float* __restrict__ xconv,
    const float* __restrict__ dbl, const float* __restrict__ xz,
    const float* __restrict__ A_log, const float* __restrict__ Dv,
    float* __restrict__ ys)
{
  int gid = blockIdx.x * 256 + threadIdx.x;
  int wv = gid >> 6;
  int lane = threadIdx.x & 63;
  int b = wv / 1536;
  int d = wv - b * 1536;
  float Ad = -__expf(A_log[d * 64 + lane]);
  float Dd = Dv[d];
  float h = 0.f;
  for (int l0 = 0; l0 < 512; l0 += 64) {
    float ykeep = 0.f;
    for (int t = 0; t < 64; ++t) {
      int row = b * 512 + l0 + t;
      float dt = delta[(size_t)row * 1536 + d];
      float u  = xconv[(size_t)row * 1536 + d];
      float bv = dbl[(size_t)row * 176 + 48 + lane];
      float cv = dbl[(size_t)row * 176 + 112 + lane];
      h = __expf(dt * Ad) * h + dt * u * bv;
      float p = h * cv;
      #pragma unroll
      for (int o = 32; o > 0; o >>= 1) p += __shfl_xor(p, o, 64);
      if (t == lane) {
        float zz = xz[(size_t)row * 3072 + 1536 + d];
        float sz = zz / (1.f + __expf(-zz));
        ykeep = (p + u * Dd) * sz;
      }
    }
    ys[((size_t)b * 1536 + d) * 512 + l0 + lane] = ykeep;
  }
}

// out[b][hh] = mean over l of bufF[(b*512+l)*768 + hh]
__global__ __launch_bounds__(256) void mean_k(const float* __restrict__ bufF,
                                              float* __restrict__ out)
{
  int hh = blockIdx.x * 256 + threadIdx.x;  // < 768
  int b = blockIdx.y;
  float s = 0.f;
  for (int l = 0; l < 512; ++l) s += bufF[((size_t)(b * 512 + l)) * 768 + hh];
  out[b * 768 + hh] = s * (1.f / 512.f);
}

extern "C" void kernel_launch(void* const* d_in, const int* in_sizes, int n_in,
                              void* d_out, int out_size, void* d_ws, size_t ws_size,
                              hipStream_t stream)
{
  const float* text      = (const float*)d_in[0];
  const float* audio     = (const float*)d_in[1];
  const float* video     = (const float*)d_in[2];
  const float* proj_w    = (const float*)d_in[3];
  const float* proj_b    = (const float*)d_in[4];
  const float* proj_ln_g = (const float*)d_in[5];
  const float* proj_ln_b = (const float*)d_in[6];
  const float* blk_ln_g  = (const float*)d_in[7];
  const float* blk_ln_b  = (const float*)d_in[8];
  const float* in_proj_w = (const float*)d_in[9];
  const float* conv_w    = (const float*)d_in[10];
  const float* conv_b    = (const float*)d_in[11];
  const float* x_proj_w  = (const float*)d_in[12];
  const float* dt_proj_w = (const float*)d_in[13];
  const float* dt_proj_b = (const float*)d_in[14];
  const float* A_log     = (const float*)d_in[15];
  const float* Dv        = (const float*)d_in[16];
  const float* out_projw = (const float*)d_in[17];
  float* out = (float*)d_out;

  // Workspace layout (floats). Total 40,894,464 floats = 163.6 MB.
  float* ws = (float*)d_ws;
  const size_t SZ768 = (size_t)4096 * 768;
  float* pre   = ws;                          // [4096,768]  (later reused as final buf)
  float* fused = pre + SZ768;                 // [4096,768]
  float* hbuf  = fused + SZ768;               // [4096,768]  (later reused as dbl [4096,176])
  float* xz    = hbuf + SZ768;                // [4096,3072]
  float* xconv = xz + (size_t)4096 * 3072;    // [4096,1536]
  float* delta = xconv + (size_t)4096 * 1536; // [4096,1536]
  float* ysb   = delta + (size_t)4096 * 1536; // [B][1536][512]
  float* dbl   = hbuf;
  float* bufF  = pre;

  // 1) fused_pre = concat(text,audio,video) @ proj_w + proj_b
  gemm_k<1, 1><<<dim3(64, 12), 256, 0, stream>>>(
      text, audio, video, proj_w, proj_b, nullptr, pre, 4096, 768, 2304, 768, 768);
  // 2) fused = LN1(pre); h = LN2(fused)
  ln2_k<<<4096, 256, 0, stream>>>(pre, proj_ln_g, proj_ln_b, blk_ln_g, blk_ln_b, fused, hbuf);
  // 3) xz = h @ in_proj_w
  gemm_k<0, 0><<<dim3(64, 48), 256, 0, stream>>>(
      hbuf, nullptr, nullptr, in_proj_w, nullptr, nullptr, xz, 4096, 3072, 768, 768, 3072);
  // 4) xconv = silu(causal_dwconv(x) + conv_b)
  conv_k<<<(4096 * 1536) / 256, 256, 0, stream>>>(xz, conv_w, conv_b, xconv);
  // 5) dbl = xconv @ x_proj_w   [4096,176]
  gemm_k<0, 0><<<dim3(64, 3), 256, 0, stream>>>(
      xconv, nullptr, nullptr, x_proj_w, nullptr, nullptr, dbl, 4096, 176, 1536, 1536, 176);
  // 6) delta = softplus(dbl[:, :48] @ dt_proj_w + dt_proj_b)
  gemm_k<0, 2><<<dim3(64, 24), 256, 0, stream>>>(
      dbl, nullptr, nullptr, dt_proj_w, dt_proj_b, nullptr, delta, 4096, 1536, 48, 176, 1536);
  // 7) selective scan + skip (u*D) + silu(z) gate -> ys in [B][DIN][L]
  scan_k<<<3072, 256, 0, stream>>>(delta, xconv, dbl, xz, A_log, Dv, ysb);
  // 8) bufF = ys @ out_proj_w + fused   (residual)
  gemm_k<2, 3><<<dim3(64, 12), 256, 0, stream>>>(
      ysb, nullptr, nullptr, out_projw, nullptr, fused, bufF, 4096, 768, 1536, 0, 768);
  // 9) out = mean over L
  mean_k<<<dim3(3, 8), 256, 0, stream>>>(bufF, out);
}